// Round 4
// baseline (4421.059 us; speedup 1.0000x reference)
//
#include <hip/hip_runtime.h>
#include <hip/hip_bf16.h>
#include <cstdint>
#include <cstddef>

typedef _Float16 f16;
typedef _Float16 f16x8 __attribute__((ext_vector_type(8)));
typedef float f32x4 __attribute__((ext_vector_type(4)));
typedef float f32x4v __attribute__((ext_vector_type(4)));
typedef unsigned long long u64;

#define B_   256
#define T_   512
#define V_   50000
#define D_   256
#define H_   256
#define A_   128
#define N4H  1024

__device__ __forceinline__ float sigmoid_f(float x) {
    return __builtin_amdgcn_rcpf(1.f + __expf(-x));
}
__device__ __forceinline__ float tanh_f(float x) {
    float e = __expf(-2.f * fabsf(x));
    float t = 1.f - 2.f * e * __builtin_amdgcn_rcpf(1.f + e);
    return copysignf(t, x);
}

// ---------------------------------------------------------------------------
// K0: weight transpose + fp32->fp16 cast.
// ---------------------------------------------------------------------------
__global__ __launch_bounds__(256) void k0_convert(
    const float* __restrict__ lstm_kernel, const float* __restrict__ w_omega,
    f16* __restrict__ WxT, f16* __restrict__ WhT, f16* __restrict__ WomT) {
    int blk = blockIdx.x;
    int tau = threadIdx.x;  // 0..255 (= k / h index)
    if (blk < N4H) {
        int n = blk;
        WxT[n * 256 + tau] = (f16)lstm_kernel[(size_t)tau * N4H + n];
        WhT[n * 256 + tau] = (f16)lstm_kernel[(size_t)(256 + tau) * N4H + n];
    } else {
        int a = blk - N4H;  // 0..127
        WomT[a * 256 + tau] = (f16)w_omega[(size_t)tau * A_ + a];
    }
}

// ---------------------------------------------------------------------------
// K1: seq_len[b] = sum_t (x[b,t] != 0); block 0 also zeroes the k3 sync flags.
// ---------------------------------------------------------------------------
__global__ __launch_bounds__(256) void k1_seqlen(
    const int* __restrict__ x, int* __restrict__ seqlen, int* __restrict__ flags) {
    __shared__ int red[256];
    int b = blockIdx.x, tau = threadIdx.x;
    if (b == 0 && tau < 32)
        __hip_atomic_store(&flags[tau * 32], 0, __ATOMIC_RELAXED,
                           __HIP_MEMORY_SCOPE_AGENT);
    int cnt = (x[b * T_ + tau] != 0) + (x[b * T_ + tau + 256] != 0);
    red[tau] = cnt;
    __syncthreads();
    for (int s = 128; s > 0; s >>= 1) {
        if (tau < s) red[tau] += red[tau + s];
        __syncthreads();
    }
    if (tau == 0) seqlen[b] = red[0];
}

// ---------------------------------------------------------------------------
// K2: Zx[i][n'] = embed[x[i]] @ Wx + bias, fp16 out.  i = b*Tc + (t - t0).
// Columns written in pair-split layout: n' = half*512 + g*128 + u'
// (n = g*256 + half*128 + u'), so each k3 half-WG reads a contiguous 512.
// ---------------------------------------------------------------------------
__global__ __launch_bounds__(256) void k2_zx(
    const int* __restrict__ x, const float* __restrict__ embed,
    const f16* __restrict__ WxT, const float* __restrict__ bias,
    f16* __restrict__ Zx, int t0, int Tc) {
    __shared__ __align__(16) f16 A_s[64][264];   // [m][k], pad 8
    __shared__ __align__(16) f16 B_s[128][72];   // [n][k-slice], pad 8
    __shared__ int tok_s[64];

    int tau  = threadIdx.x;
    int bm   = blockIdx.x;
    int i0   = bm * 64;
    int wave = tau >> 6, lane = tau & 63;
    int q = lane >> 4, c = lane & 15;

    if (tau < 64) {
        int i  = i0 + tau;
        int bb = i / Tc, tr = i - bb * Tc;
        tok_s[tau] = x[bb * T_ + t0 + tr];
    }
    __syncthreads();

    // gather A: 64 rows x 256 f32 -> fp16 LDS. 4 threads/row, 16 float4 each.
    {
        int r = tau >> 2, quarter = tau & 3;
        const float4* src =
            (const float4*)(embed + (size_t)tok_s[r] * D_ + quarter * 64);
        f16* dst = &A_s[r][quarter * 64];
#pragma unroll
        for (int j = 0; j < 16; j++) {
            float4 v = src[j];
            dst[j * 4 + 0] = (f16)v.x;
            dst[j * 4 + 1] = (f16)v.y;
            dst[j * 4 + 2] = (f16)v.z;
            dst[j * 4 + 3] = (f16)v.w;
        }
    }

    for (int np = 0; np < 8; np++) {
        f32x4 acc[8];
#pragma unroll
        for (int ni = 0; ni < 8; ni++) acc[ni] = (f32x4){0.f, 0.f, 0.f, 0.f};

        for (int kt = 0; kt < 4; kt++) {
            __syncthreads();  // previous B_s consumers done
            {
                int n = tau >> 1, half = tau & 1;
                const f16x8* src = (const f16x8*)(WxT +
                    (size_t)(np * 128 + n) * 256 + kt * 64 + half * 32);
                f16x8* dst = (f16x8*)&B_s[n][half * 32];
#pragma unroll
                for (int j = 0; j < 4; j++) dst[j] = src[j];
            }
            __syncthreads();
#pragma unroll
            for (int s = 0; s < 2; s++) {
                f16x8 afrag =
                    *(const f16x8*)&A_s[wave * 16 + c][kt * 64 + s * 32 + q * 8];
#pragma unroll
                for (int ni = 0; ni < 8; ni++) {
                    f16x8 bfrag = *(const f16x8*)&B_s[ni * 16 + c][s * 32 + q * 8];
                    acc[ni] = __builtin_amdgcn_mfma_f32_16x16x32_f16(
                        afrag, bfrag, acc[ni], 0, 0, 0);
                }
            }
        }
        // epilogue for this n-pass (permuted column write)
#pragma unroll
        for (int ni = 0; ni < 8; ni++) {
            int n   = np * 128 + ni * 16 + c;
            int g   = n >> 8, rem = n & 255;
            int np2 = (rem >> 7) * 512 + g * 128 + (rem & 127);
            float bv = bias[n];
#pragma unroll
            for (int r = 0; r < 4; r++) {
                int row = i0 + wave * 16 + q * 4 + r;
                Zx[(size_t)row * N4H + np2] = (f16)(acc[ni][r] + bv);
            }
        }
    }
}

// ---------------------------------------------------------------------------
// K3: persistent LSTM, Wh register-resident (asm-pinned). 32 WGs x 512 thr.
// pair = wgid & 15 owns batch rows [16*pair, +16); half = wgid >> 4 owns
// hidden units [128*half, +128) for all 4 gates (partner = wgid ^ 16 -> same
// XCD under round-robin dispatch). Per step: MFMA (B in regs) -> gates ->
// agent-scope hex stores -> per-wave release add -> all-lane poll of partner
// flag -> acquire -> pull partner 4KB -> ONE __syncthreads().
// ---------------------------------------------------------------------------
__global__ __launch_bounds__(512, 2) void k3_lstm(
    const f16* __restrict__ Zx, const f16* __restrict__ WhT,
    const int* __restrict__ seqlen, f16* __restrict__ outs,
    f16* __restrict__ Hstate, float* __restrict__ Cstate,
    f16* __restrict__ Hex, int* __restrict__ flags,
    int t0, int Tc, int first, int last) {
    __shared__ __align__(16) f16 Zx_s[2][16][520];  // [parity][row][512 cols]
    __shared__ __align__(16) f16 h_s[2][16][264];   // [parity][row][k]

    int tau  = threadIdx.x;
    int w    = tau >> 6, lane = tau & 63;
    int q = lane >> 4, c = lane & 15;
    int wgid = blockIdx.x;
    int pair = wgid & 15, half = wgid >> 4;
    int b0 = pair * 16;
    int u0 = half * 128, pu0 = (half ^ 1) * 128;
    int u  = u0 + w * 16 + c;   // this lane's hidden unit
    int zu = w * 16 + c;        // column inside our 512-chunk (per gate)

    int* myflag = &flags[wgid * 32];
    int* pflag  = &flags[(wgid ^ 16) * 32];
    f16* hex_my = Hex + (size_t)wgid * 2 * 2048;         // [parity][16][128]
    f16* hex_pr = Hex + (size_t)(wgid ^ 16) * 2 * 2048;

    // ---- load register-resident Wh fragments (once), pin via opaque asm ----
    f16x8 whf[4][8];
#pragma unroll
    for (int g = 0; g < 4; g++)
#pragma unroll
        for (int kc = 0; kc < 8; kc++)
            whf[g][kc] = *(const f16x8*)(WhT +
                (size_t)(g * 256 + u0 + w * 16 + c) * 256 + kc * 32 + q * 8);
#pragma unroll
    for (int g = 0; g < 4; g++)
#pragma unroll
        for (int kc = 0; kc < 8; kc++) {
            f32x4v tmp = __builtin_bit_cast(f32x4v, whf[g][kc]);
            asm volatile("" : "+v"(tmp));
            whf[g][kc] = __builtin_bit_cast(f16x8, tmp);
        }

    // ---- init h_s ----
    if (first) {
        for (int idx = tau; idx < 2 * 16 * 264; idx += 512)
            ((f16*)h_s)[idx] = (f16)0.f;
    } else {
        int parity = t0 & 1;
        for (int idx = tau; idx < 16 * 256; idx += 512) {
            int r = idx >> 8, k = idx & 255;
            h_s[parity][r][k] = Hstate[(b0 + r) * H_ + k];
        }
    }

    float cst[4];
    int   sl[4];
#pragma unroll
    for (int r = 0; r < 4; r++) {
        int row = q * 4 + r;
        cst[r] = first ? 0.f : Cstate[(b0 + row) * H_ + u];
        sl[r]  = seqlen[b0 + row];
    }

    // Zx staging geometry: thread stages 32 B of row (tau>>5), cols (tau&31)*16
    int r_st = tau >> 5;
    int cc   = (tau & 31) * 16;
    const f16* zxrow = Zx + ((size_t)(b0 + r_st) * Tc) * N4H + half * 512 + cc;

    // prologue: fill Zx_s for step 0
    {
        const f16x8* src = (const f16x8*)zxrow;
        f16x8* dst = (f16x8*)&Zx_s[t0 & 1][r_st][cc];
        dst[0] = src[0];
        dst[1] = src[1];
    }
    // partner-read geometry: thread reads 8 B: row tau>>5, units (tau&31)*4
    int rr = tau >> 5;
    int uu = (tau & 31) * 4;

    __syncthreads();

    for (int tt = 0; tt < Tc; tt++) {
        int t  = t0 + tt;
        int pr = t & 1, pw = pr ^ 1;

        // prefetch Zx for step tt+1 (in flight across MFMA+gate phase)
        int tn = (tt + 1 < Tc) ? tt + 1 : tt;
        const f16x8* psrc = (const f16x8*)(zxrow + (size_t)tn * N4H);
        f16x8 z0 = psrc[0];
        f16x8 z1 = psrc[1];

        // recurrent GEMM: 4 gate tiles, K=256, B entirely in registers
        f32x4 acc[4];
#pragma unroll
        for (int g = 0; g < 4; g++) acc[g] = (f32x4){0.f, 0.f, 0.f, 0.f};
#pragma unroll
        for (int kc = 0; kc < 8; kc++) {
            f16x8 afrag = *(const f16x8*)&h_s[pr][c][kc * 32 + q * 8];
#pragma unroll
            for (int g = 0; g < 4; g++) {
                acc[g] = __builtin_amdgcn_mfma_f32_16x16x32_f16(
                    afrag, whf[g][kc], acc[g], 0, 0, 0);
            }
        }

        // gates + state update (C layout: col=c, row=q*4+r)
#pragma unroll
        for (int r = 0; r < 4; r++) {
            int row = q * 4 + r;
            float zi = acc[0][r] + (float)Zx_s[pr][row][0 * 128 + zu];
            float zj = acc[1][r] + (float)Zx_s[pr][row][1 * 128 + zu];
            float zf = acc[2][r] + (float)Zx_s[pr][row][2 * 128 + zu];
            float zo = acc[3][r] + (float)Zx_s[pr][row][3 * 128 + zu];
            float ig = sigmoid_f(zi);
            float jg = tanh_f(zj);
            float fg = sigmoid_f(zf + 1.f);
            float og = sigmoid_f(zo);
            float cn = cst[r] * fg + ig * jg;
            float hn = tanh_f(cn) * og;
            bool  m  = (t < sl[r]);
            cst[r]   = m ? cn : cst[r];
            float hold = (float)h_s[pr][row][u];
            f16 hkeep = (f16)(m ? hn : hold);
            h_s[pw][row][u] = hkeep;
            short hs = __builtin_bit_cast(short, hkeep);
            __hip_atomic_store((short*)(hex_my + pw * 2048 + row * 128 +
                                        (u - u0)),
                               hs, __ATOMIC_RELAXED, __HIP_MEMORY_SCOPE_AGENT);
            outs[((size_t)(b0 + row) * T_ + t) * H_ + u] = (f16)(m ? hn : 0.f);
        }

        // consume Zx prefetch into other parity (before the release drain)
        {
            f16x8* dst = (f16x8*)&Zx_s[pw][r_st][cc];
            dst[0] = z0;
            dst[1] = z1;
        }

        // per-wave release: orders this wave's hex stores (vmcnt drain is
        // wave-local), then all lanes poll partner's counter
        if (lane == 0)
            __hip_atomic_fetch_add(myflag, 1, __ATOMIC_RELEASE,
                                   __HIP_MEMORY_SCOPE_AGENT);
        int target = 8 * (t + 1);
        while (__hip_atomic_load(pflag, __ATOMIC_RELAXED,
                                 __HIP_MEMORY_SCOPE_AGENT) < target) {}
        __builtin_amdgcn_fence(__ATOMIC_ACQUIRE, "agent");

        // pull partner's h half (8 B per lane)
        {
            u64 v = __hip_atomic_load(
                (const u64*)(hex_pr + pw * 2048 + rr * 128 + uu),
                __ATOMIC_RELAXED, __HIP_MEMORY_SCOPE_AGENT);
            *(u64*)&h_s[pw][rr][pu0 + uu] = v;
        }

        __syncthreads();  // h_s[pw] + Zx_s[pw] fully assembled for next step
    }

    if (!last) {
        int parity = (t0 + Tc) & 1;
        for (int idx = tau; idx < 16 * 128; idx += 512) {
            int r = idx >> 7, k = u0 + (idx & 127);
            Hstate[(b0 + r) * H_ + k] = h_s[parity][r][k];
        }
#pragma unroll
        for (int r = 0; r < 4; r++)
            Cstate[(b0 + q * 4 + r) * H_ + u] = cst[r];
    }
}

// ---------------------------------------------------------------------------
// K4: attention + head. One WG (256 thr) per batch row.
// ---------------------------------------------------------------------------
__global__ __launch_bounds__(256) void k4_attn(
    const f16* __restrict__ outs, const f16* __restrict__ WomT,
    const float* __restrict__ b_omega, const float* __restrict__ u_omega,
    const float* __restrict__ w, const float* __restrict__ bfin,
    float* __restrict__ out) {
    __shared__ __align__(16) f16 A_s[64][264];
    __shared__ __align__(16) f16 val_s[64][132];
    __shared__ float u_s[128];
    __shared__ float vu_s[512];
    __shared__ float red0[256], red1[256];

    int b = blockIdx.x, tau = threadIdx.x;
    int wave = tau >> 6, lane = tau & 63;
    int q = lane >> 4, c = lane & 15;

    if (tau < 128) u_s[tau] = u_omega[tau];
    float bom[8];
#pragma unroll
    for (int ni = 0; ni < 8; ni++) bom[ni] = b_omega[ni * 16 + c];

    for (int ch = 0; ch < 8; ch++) {
        int t0c = ch * 64;
        __syncthreads();  // protects A_s/val_s reuse (+ covers u_s init)
        {   // stage 64 rows of outs
            int r = tau >> 2, seg = tau & 3;
            const f16x8* src =
                (const f16x8*)(outs + ((size_t)b * T_ + t0c + r) * H_ + seg * 64);
            f16x8* dst = (f16x8*)&A_s[r][seg * 64];
#pragma unroll
            for (int j = 0; j < 8; j++) dst[j] = src[j];
        }
        __syncthreads();

        f32x4 acc[8];
#pragma unroll
        for (int ni = 0; ni < 8; ni++) acc[ni] = (f32x4){0.f, 0.f, 0.f, 0.f};
#pragma unroll
        for (int kc = 0; kc < 8; kc++) {
            f16x8 afrag = *(const f16x8*)&A_s[wave * 16 + c][kc * 32 + q * 8];
#pragma unroll
            for (int ni = 0; ni < 8; ni++) {
                f16x8 bfrag = *(const f16x8*)(WomT +
                    (size_t)(ni * 16 + c) * 256 + kc * 32 + q * 8);
                acc[ni] = __builtin_amdgcn_mfma_f32_16x16x32_f16(
                    afrag, bfrag, acc[ni], 0, 0, 0);
            }
        }
#pragma unroll
        for (int ni = 0; ni < 8; ni++) {
#pragma unroll
            for (int r = 0; r < 4; r++) {
                val_s[wave * 16 + q * 4 + r][ni * 16 + c] =
                    (f16)tanh_f(acc[ni][r] + bom[ni]);
            }
        }
        __syncthreads();
        if (tau < 64) {
            float s = 0.f;
#pragma unroll 8
            for (int a = 0; a < 128; a++) s += (float)val_s[tau][a] * u_s[a];
            vu_s[t0c + tau] = s;
        }
    }
    __syncthreads();

    // softmax over T=512
    red0[tau] = fmaxf(vu_s[tau], vu_s[tau + 256]);
    __syncthreads();
    for (int s = 128; s > 0; s >>= 1) {
        if (tau < s) red0[tau] = fmaxf(red0[tau], red0[tau + s]);
        __syncthreads();
    }
    float mx = red0[0];
    __syncthreads();
    float e0 = __expf(vu_s[tau] - mx), e1 = __expf(vu_s[tau + 256] - mx);
    red0[tau] = e0 + e1;
    __syncthreads();
    for (int s = 128; s > 0; s >>= 1) {
        if (tau < s) red0[tau] += red0[tau + s];
        __syncthreads();
    }
    float inv = 1.f / red0[0];
    __syncthreads();
    vu_s[tau]       = e0 * inv;
    vu_s[tau + 256] = e1 * inv;
    __syncthreads();

    // last[h] = sum_t alpha[t] * outs[b][t][h]   (tau = h)
    float lastv = 0.f;
#pragma unroll 4
    for (int t = 0; t < T_; t++)
        lastv += vu_s[t] * (float)outs[((size_t)b * T_ + t) * H_ + tau];

    // logits + 2-class softmax
    red0[tau] = lastv * w[tau * 2 + 0];
    red1[tau] = lastv * w[tau * 2 + 1];
    __syncthreads();
    for (int s = 128; s > 0; s >>= 1) {
        if (tau < s) {
            red0[tau] += red0[tau + s];
            red1[tau] += red1[tau + s];
        }
        __syncthreads();
    }
    if (tau == 0) {
        float l0 = red0[0] + bfin[0], l1 = red1[0] + bfin[1];
        float mm = fmaxf(l0, l1);
        float a0 = __expf(l0 - mm), a1 = __expf(l1 - mm);
        float den = a0 + a1;
        out[b * 2 + 0] = a0 / den;
        out[b * 2 + 1] = a1 / den;
    }
}

// ---------------------------------------------------------------------------
extern "C" void kernel_launch(void* const* d_in, const int* in_sizes, int n_in,
                              void* d_out, int out_size, void* d_ws,
                              size_t ws_size, hipStream_t stream) {
    const int*   x           = (const int*)d_in[0];
    const float* embed       = (const float*)d_in[1];
    const float* lstm_kernel = (const float*)d_in[2];
    const float* lstm_bias   = (const float*)d_in[3];
    const float* w_omega     = (const float*)d_in[4];
    const float* b_omega     = (const float*)d_in[5];
    const float* u_omega     = (const float*)d_in[6];
    const float* w           = (const float*)d_in[7];
    const float* bfin        = (const float*)d_in[8];
    float*       out         = (float*)d_out;

    char* ws = (char*)d_ws;
    f16*   WxT    = (f16*)(ws + 0);              //  524288 B
    f16*   WhT    = (f16*)(ws + 524288);         //  524288 B
    f16*   WomT   = (f16*)(ws + 1048576);        //   65536 B
    int*   seqlen = (int*)(ws + 1114112);        //    1024 B
    f16*   Hstate = (f16*)(ws + 1115136);        //  131072 B
    float* Cstate = (float*)(ws + 1246208);      //  262144 B
    f16*   Hex    = (f16*)(ws + 1508352);        //  262144 B (32 wg x 2 x 4KB)
    int*   flags  = (int*)(ws + 1770496);        //    4096 B (32 x 128 B)
    f16*   outs   = (f16*)(ws + 1774592);        // 67108864 B
    f16*   Zx     = (f16*)(ws + 1774592 + 67108864);

    const size_t fixed = 1774592ull + 67108864ull;
    int nch = 1;
    while (nch < 16 && fixed + 268435456ull / (size_t)nch > ws_size) nch <<= 1;
    int Tc = T_ / nch;

    k0_convert<<<1152, 256, 0, stream>>>(lstm_kernel, w_omega, WxT, WhT, WomT);
    k1_seqlen<<<256, 256, 0, stream>>>(x, seqlen, flags);
    for (int chk = 0; chk < nch; chk++) {
        int t0 = chk * Tc;
        k2_zx<<<(B_ * Tc) / 64, 256, 0, stream>>>(x, embed, WxT, lstm_bias, Zx,
                                                  t0, Tc);
        k3_lstm<<<32, 512, 0, stream>>>(Zx, WhT, seqlen, outs, Hstate, Cstate,
                                        Hex, flags, t0, Tc, chk == 0 ? 1 : 0,
                                        chk == nch - 1 ? 1 : 0);
    }
    k4_attn<<<256, 256, 0, stream>>>(outs, WomT, b_omega, u_omega, w, bfin, out);
}

// Round 5
// 2269.767 us; speedup vs baseline: 1.9478x; 1.9478x over previous
//
#include <hip/hip_runtime.h>
#include <hip/hip_bf16.h>
#include <cstdint>
#include <cstddef>

typedef _Float16 f16;
typedef _Float16 f16x8 __attribute__((ext_vector_type(8)));
typedef float f32x4 __attribute__((ext_vector_type(4)));
typedef unsigned long long u64;

#define B_   256
#define T_   512
#define V_   50000
#define D_   256
#define H_   256
#define A_   128
#define N4H  1024

__device__ __forceinline__ float sigmoid_f(float x) {
    return __builtin_amdgcn_rcpf(1.f + __expf(-x));
}
__device__ __forceinline__ float tanh_f(float x) {
    float e = __expf(-2.f * fabsf(x));
    float t = 1.f - 2.f * e * __builtin_amdgcn_rcpf(1.f + e);
    return copysignf(t, x);
}

// ---------------------------------------------------------------------------
// K0: weight transpose + fp32->fp16 cast.
// ---------------------------------------------------------------------------
__global__ __launch_bounds__(256) void k0_convert(
    const float* __restrict__ lstm_kernel, const float* __restrict__ w_omega,
    f16* __restrict__ WxT, f16* __restrict__ WhT, f16* __restrict__ WomT) {
    int blk = blockIdx.x;
    int tau = threadIdx.x;  // 0..255 (= k / h index)
    if (blk < N4H) {
        int n = blk;
        WxT[n * 256 + tau] = (f16)lstm_kernel[(size_t)tau * N4H + n];
        WhT[n * 256 + tau] = (f16)lstm_kernel[(size_t)(256 + tau) * N4H + n];
    } else {
        int a = blk - N4H;  // 0..127
        WomT[a * 256 + tau] = (f16)w_omega[(size_t)tau * A_ + a];
    }
}

// ---------------------------------------------------------------------------
// K1: seq_len[b] = sum_t (x[b,t] != 0); block 0 also zeroes the k3 sync flags.
// ---------------------------------------------------------------------------
__global__ __launch_bounds__(256) void k1_seqlen(
    const int* __restrict__ x, int* __restrict__ seqlen, int* __restrict__ flags) {
    __shared__ int red[256];
    int b = blockIdx.x, tau = threadIdx.x;
    if (b == 0 && tau < 32)
        __hip_atomic_store(&flags[tau * 32], 0, __ATOMIC_RELAXED,
                           __HIP_MEMORY_SCOPE_AGENT);
    int cnt = (x[b * T_ + tau] != 0) + (x[b * T_ + tau + 256] != 0);
    red[tau] = cnt;
    __syncthreads();
    for (int s = 128; s > 0; s >>= 1) {
        if (tau < s) red[tau] += red[tau + s];
        __syncthreads();
    }
    if (tau == 0) seqlen[b] = red[0];
}

// ---------------------------------------------------------------------------
// K2: Zx[i][n'] = embed[x[i]] @ Wx + bias, fp16 out.  i = b*Tc + (t - t0).
// Columns written in pair-split layout: n' = half*512 + g*128 + u'
// (n = g*256 + half*128 + u'), so each k3 half-WG reads a contiguous 512.
// ---------------------------------------------------------------------------
__global__ __launch_bounds__(256) void k2_zx(
    const int* __restrict__ x, const float* __restrict__ embed,
    const f16* __restrict__ WxT, const float* __restrict__ bias,
    f16* __restrict__ Zx, int t0, int Tc) {
    __shared__ __align__(16) f16 A_s[64][264];   // [m][k], pad 8
    __shared__ __align__(16) f16 B_s[128][72];   // [n][k-slice], pad 8
    __shared__ int tok_s[64];

    int tau  = threadIdx.x;
    int bm   = blockIdx.x;
    int i0   = bm * 64;
    int wave = tau >> 6, lane = tau & 63;
    int q = lane >> 4, c = lane & 15;

    if (tau < 64) {
        int i  = i0 + tau;
        int bb = i / Tc, tr = i - bb * Tc;
        tok_s[tau] = x[bb * T_ + t0 + tr];
    }
    __syncthreads();

    // gather A: 64 rows x 256 f32 -> fp16 LDS. 4 threads/row, 16 float4 each.
    {
        int r = tau >> 2, quarter = tau & 3;
        const float4* src =
            (const float4*)(embed + (size_t)tok_s[r] * D_ + quarter * 64);
        f16* dst = &A_s[r][quarter * 64];
#pragma unroll
        for (int j = 0; j < 16; j++) {
            float4 v = src[j];
            dst[j * 4 + 0] = (f16)v.x;
            dst[j * 4 + 1] = (f16)v.y;
            dst[j * 4 + 2] = (f16)v.z;
            dst[j * 4 + 3] = (f16)v.w;
        }
    }

    for (int np = 0; np < 8; np++) {
        f32x4 acc[8];
#pragma unroll
        for (int ni = 0; ni < 8; ni++) acc[ni] = (f32x4){0.f, 0.f, 0.f, 0.f};

        for (int kt = 0; kt < 4; kt++) {
            __syncthreads();  // previous B_s consumers done
            {
                int n = tau >> 1, half = tau & 1;
                const f16x8* src = (const f16x8*)(WxT +
                    (size_t)(np * 128 + n) * 256 + kt * 64 + half * 32);
                f16x8* dst = (f16x8*)&B_s[n][half * 32];
#pragma unroll
                for (int j = 0; j < 4; j++) dst[j] = src[j];
            }
            __syncthreads();
#pragma unroll
            for (int s = 0; s < 2; s++) {
                f16x8 afrag =
                    *(const f16x8*)&A_s[wave * 16 + c][kt * 64 + s * 32 + q * 8];
#pragma unroll
                for (int ni = 0; ni < 8; ni++) {
                    f16x8 bfrag = *(const f16x8*)&B_s[ni * 16 + c][s * 32 + q * 8];
                    acc[ni] = __builtin_amdgcn_mfma_f32_16x16x32_f16(
                        afrag, bfrag, acc[ni], 0, 0, 0);
                }
            }
        }
        // epilogue for this n-pass (permuted column write)
#pragma unroll
        for (int ni = 0; ni < 8; ni++) {
            int n   = np * 128 + ni * 16 + c;
            int g   = n >> 8, rem = n & 255;
            int np2 = (rem >> 7) * 512 + g * 128 + (rem & 127);
            float bv = bias[n];
#pragma unroll
            for (int r = 0; r < 4; r++) {
                int row = i0 + wave * 16 + q * 4 + r;
                Zx[(size_t)row * N4H + np2] = (f16)(acc[ni][r] + bv);
            }
        }
    }
}

// ---------------------------------------------------------------------------
// K3: persistent LSTM, Wh held in AGPRs (explicit v_accvgpr stash). 32 WGs x
// 512 thr. pair = wgid>>1 owns batch rows [16*pair,+16); half = wgid&1 owns
// hidden units [128*half,+128) for all 4 gates. 128 AGPRs/lane hold the
// 256 KB half-Wh slice; per use a volatile v_accvgpr_read rebuilds the
// B-fragment (VALU move, no memory traffic). Sync protocol = round-3
// measured form: lane-0 release store + s_sleep poll + acquire, 3 barriers.
// ---------------------------------------------------------------------------
__global__ __launch_bounds__(512, 2) void k3_lstm(
    const f16* __restrict__ Zx, const f16* __restrict__ WhT,
    const int* __restrict__ seqlen, f16* __restrict__ outs,
    f16* __restrict__ Hstate, float* __restrict__ Cstate,
    f16* __restrict__ Hex, int* __restrict__ flags,
    int t0, int Tc, int first, int last) {
    __shared__ __align__(16) f16 Zx_s[2][16][520];  // [parity][row][512 cols]
    __shared__ __align__(16) f16 h_s[2][16][264];   // [parity][row][k]

    int tau  = threadIdx.x;
    int w    = tau >> 6, lane = tau & 63;
    int q = lane >> 4, c = lane & 15;
    int wgid = blockIdx.x;
    int pair = wgid >> 1, half = wgid & 1;
    int b0 = pair * 16;
    int u0 = half * 128, pu0 = (half ^ 1) * 128;
    int u  = u0 + w * 16 + c;   // this lane's hidden unit
    int zu = w * 16 + c;        // column inside our 512-chunk (per gate)

    int* myflag = &flags[wgid * 32];
    int* pflag  = &flags[(wgid ^ 1) * 32];
    f16* hex_my = Hex + (size_t)wgid * 2 * 2048;         // [parity][16][128]
    f16* hex_pr = Hex + (size_t)(wgid ^ 1) * 2 * 2048;

    // ---- load Wh fragments once and stash into AGPRs ----
    float wha[4][8][4];  // SROA -> 128 individual "a"-class scalars
#pragma unroll
    for (int g = 0; g < 4; g++)
#pragma unroll
        for (int kc = 0; kc < 8; kc++) {
            f16x8 f = *(const f16x8*)(WhT +
                (size_t)(g * 256 + u0 + w * 16 + c) * 256 + kc * 32 + q * 8);
            f32x4 t = __builtin_bit_cast(f32x4, f);
#pragma unroll
            for (int d = 0; d < 4; d++)
                asm volatile("v_accvgpr_write_b32 %0, %1"
                             : "=a"(wha[g][kc][d]) : "v"(t[d]));
        }

    // ---- init h_s ----
    if (first) {
        for (int idx = tau; idx < 2 * 16 * 264; idx += 512)
            ((f16*)h_s)[idx] = (f16)0.f;
    } else {
        int parity = t0 & 1;
        for (int idx = tau; idx < 16 * 256; idx += 512) {
            int r = idx >> 8, k = idx & 255;
            h_s[parity][r][k] = Hstate[(b0 + r) * H_ + k];
        }
    }

    float cst[4];
    int   sl[4];
#pragma unroll
    for (int r = 0; r < 4; r++) {
        int row = q * 4 + r;
        cst[r] = first ? 0.f : Cstate[(b0 + row) * H_ + u];
        sl[r]  = seqlen[b0 + row];
    }

    // Zx staging geometry: thread stages 32 B of row (tau>>5), cols (tau&31)*16
    int r_st = tau >> 5;
    int cc   = (tau & 31) * 16;
    const f16* zxrow = Zx + ((size_t)(b0 + r_st) * Tc) * N4H + half * 512 + cc;

    // prologue: fill Zx_s for step 0
    {
        const f16x8* src = (const f16x8*)zxrow;
        f16x8* dst = (f16x8*)&Zx_s[t0 & 1][r_st][cc];
        dst[0] = src[0];
        dst[1] = src[1];
    }
    // partner-read geometry: thread reads 8 B: row tau>>5, units (tau&31)*4
    int rr = tau >> 5;
    int uu = (tau & 31) * 4;

    __syncthreads();

    for (int tt = 0; tt < Tc; tt++) {
        int t  = t0 + tt;
        int pr = t & 1, pw = pr ^ 1;

        // prefetch Zx for step tt+1 (in flight across MFMA+gate phase)
        int tn = (tt + 1 < Tc) ? tt + 1 : tt;
        const f16x8* psrc = (const f16x8*)(zxrow + (size_t)tn * N4H);
        f16x8 z0 = psrc[0];
        f16x8 z1 = psrc[1];

        // recurrent GEMM: 4 gate tiles, K=256, B rebuilt from AGPRs per use
        f32x4 acc[4];
#pragma unroll
        for (int g = 0; g < 4; g++) acc[g] = (f32x4){0.f, 0.f, 0.f, 0.f};
#pragma unroll
        for (int kc = 0; kc < 8; kc++) {
            f16x8 afrag = *(const f16x8*)&h_s[pr][c][kc * 32 + q * 8];
#pragma unroll
            for (int g = 0; g < 4; g++) {
                f32x4 bv;
#pragma unroll
                for (int d = 0; d < 4; d++)
                    asm volatile("v_accvgpr_read_b32 %0, %1"
                                 : "=v"(bv[d]) : "a"(wha[g][kc][d]));
                f16x8 bfrag = __builtin_bit_cast(f16x8, bv);
                acc[g] = __builtin_amdgcn_mfma_f32_16x16x32_f16(
                    afrag, bfrag, acc[g], 0, 0, 0);
            }
        }

        // gates + state update (C layout: col=c, row=q*4+r)
#pragma unroll
        for (int r = 0; r < 4; r++) {
            int row = q * 4 + r;
            float zi = acc[0][r] + (float)Zx_s[pr][row][0 * 128 + zu];
            float zj = acc[1][r] + (float)Zx_s[pr][row][1 * 128 + zu];
            float zf = acc[2][r] + (float)Zx_s[pr][row][2 * 128 + zu];
            float zo = acc[3][r] + (float)Zx_s[pr][row][3 * 128 + zu];
            float ig = sigmoid_f(zi);
            float jg = tanh_f(zj);
            float fg = sigmoid_f(zf + 1.f);
            float og = sigmoid_f(zo);
            float cn = cst[r] * fg + ig * jg;
            float hn = tanh_f(cn) * og;
            bool  m  = (t < sl[r]);
            cst[r]   = m ? cn : cst[r];
            float hold = (float)h_s[pr][row][u];
            f16 hkeep = (f16)(m ? hn : hold);
            h_s[pw][row][u] = hkeep;
            short hs = __builtin_bit_cast(short, hkeep);
            __hip_atomic_store((short*)(hex_my + pw * 2048 + row * 128 +
                                        (u - u0)),
                               hs, __ATOMIC_RELAXED, __HIP_MEMORY_SCOPE_AGENT);
            outs[((size_t)(b0 + row) * T_ + t) * H_ + u] = (f16)(m ? hn : 0.f);
        }

        // consume Zx prefetch into other parity
        {
            f16x8* dst = (f16x8*)&Zx_s[pw][r_st][cc];
            dst[0] = z0;
            dst[1] = z1;
        }

        __syncthreads();  // drains all lanes' hex stores (vmcnt(0) at barrier)

        if (tau == 0) {
            __hip_atomic_store(myflag, t + 1, __ATOMIC_RELEASE,
                               __HIP_MEMORY_SCOPE_AGENT);
            while (__hip_atomic_load(pflag, __ATOMIC_RELAXED,
                                     __HIP_MEMORY_SCOPE_AGENT) < t + 1)
                __builtin_amdgcn_s_sleep(1);
            __builtin_amdgcn_fence(__ATOMIC_ACQUIRE, "agent");
        }
        __syncthreads();

        // pull partner's h half from L3 (cache-bypassing 8-B loads)
        {
            u64 v = __hip_atomic_load(
                (const u64*)(hex_pr + pw * 2048 + rr * 128 + uu),
                __ATOMIC_RELAXED, __HIP_MEMORY_SCOPE_AGENT);
            *(u64*)&h_s[pw][rr][pu0 + uu] = v;
        }
        __syncthreads();  // h_s[pw] fully assembled for next step
    }

    if (!last) {
        int parity = (t0 + Tc) & 1;
        for (int idx = tau; idx < 16 * 128; idx += 512) {
            int r = idx >> 7, k = u0 + (idx & 127);
            Hstate[(b0 + r) * H_ + k] = h_s[parity][r][k];
        }
#pragma unroll
        for (int r = 0; r < 4; r++)
            Cstate[(b0 + q * 4 + r) * H_ + u] = cst[r];
    }
}

// ---------------------------------------------------------------------------
// K4: attention + head. One WG (256 thr) per batch row.
// ---------------------------------------------------------------------------
__global__ __launch_bounds__(256) void k4_attn(
    const f16* __restrict__ outs, const f16* __restrict__ WomT,
    const float* __restrict__ b_omega, const float* __restrict__ u_omega,
    const float* __restrict__ w, const float* __restrict__ bfin,
    float* __restrict__ out) {
    __shared__ __align__(16) f16 A_s[64][264];
    __shared__ __align__(16) f16 val_s[64][132];
    __shared__ float u_s[128];
    __shared__ float vu_s[512];
    __shared__ float red0[256], red1[256];

    int b = blockIdx.x, tau = threadIdx.x;
    int wave = tau >> 6, lane = tau & 63;
    int q = lane >> 4, c = lane & 15;

    if (tau < 128) u_s[tau] = u_omega[tau];
    float bom[8];
#pragma unroll
    for (int ni = 0; ni < 8; ni++) bom[ni] = b_omega[ni * 16 + c];

    for (int ch = 0; ch < 8; ch++) {
        int t0c = ch * 64;
        __syncthreads();  // protects A_s/val_s reuse (+ covers u_s init)
        {   // stage 64 rows of outs
            int r = tau >> 2, seg = tau & 3;
            const f16x8* src =
                (const f16x8*)(outs + ((size_t)b * T_ + t0c + r) * H_ + seg * 64);
            f16x8* dst = (f16x8*)&A_s[r][seg * 64];
#pragma unroll
            for (int j = 0; j < 8; j++) dst[j] = src[j];
        }
        __syncthreads();

        f32x4 acc[8];
#pragma unroll
        for (int ni = 0; ni < 8; ni++) acc[ni] = (f32x4){0.f, 0.f, 0.f, 0.f};
#pragma unroll
        for (int kc = 0; kc < 8; kc++) {
            f16x8 afrag = *(const f16x8*)&A_s[wave * 16 + c][kc * 32 + q * 8];
#pragma unroll
            for (int ni = 0; ni < 8; ni++) {
                f16x8 bfrag = *(const f16x8*)(WomT +
                    (size_t)(ni * 16 + c) * 256 + kc * 32 + q * 8);
                acc[ni] = __builtin_amdgcn_mfma_f32_16x16x32_f16(
                    afrag, bfrag, acc[ni], 0, 0, 0);
            }
        }
#pragma unroll
        for (int ni = 0; ni < 8; ni++) {
#pragma unroll
            for (int r = 0; r < 4; r++) {
                val_s[wave * 16 + q * 4 + r][ni * 16 + c] =
                    (f16)tanh_f(acc[ni][r] + bom[ni]);
            }
        }
        __syncthreads();
        if (tau < 64) {
            float s = 0.f;
#pragma unroll 8
            for (int a = 0; a < 128; a++) s += (float)val_s[tau][a] * u_s[a];
            vu_s[t0c + tau] = s;
        }
    }
    __syncthreads();

    // softmax over T=512
    red0[tau] = fmaxf(vu_s[tau], vu_s[tau + 256]);
    __syncthreads();
    for (int s = 128; s > 0; s >>= 1) {
        if (tau < s) red0[tau] = fmaxf(red0[tau], red0[tau + s]);
        __syncthreads();
    }
    float mx = red0[0];
    __syncthreads();
    float e0 = __expf(vu_s[tau] - mx), e1 = __expf(vu_s[tau + 256] - mx);
    red0[tau] = e0 + e1;
    __syncthreads();
    for (int s = 128; s > 0; s >>= 1) {
        if (tau < s) red0[tau] += red0[tau + s];
        __syncthreads();
    }
    float inv = 1.f / red0[0];
    __syncthreads();
    vu_s[tau]       = e0 * inv;
    vu_s[tau + 256] = e1 * inv;
    __syncthreads();

    // last[h] = sum_t alpha[t] * outs[b][t][h]   (tau = h)
    float lastv = 0.f;
#pragma unroll 4
    for (int t = 0; t < T_; t++)
        lastv += vu_s[t] * (float)outs[((size_t)b * T_ + t) * H_ + tau];

    // logits + 2-class softmax
    red0[tau] = lastv * w[tau * 2 + 0];
    red1[tau] = lastv * w[tau * 2 + 1];
    __syncthreads();
    for (int s = 128; s > 0; s >>= 1) {
        if (tau < s) {
            red0[tau] += red0[tau + s];
            red1[tau] += red1[tau + s];
        }
        __syncthreads();
    }
    if (tau == 0) {
        float l0 = red0[0] + bfin[0], l1 = red1[0] + bfin[1];
        float mm = fmaxf(l0, l1);
        float a0 = __expf(l0 - mm), a1 = __expf(l1 - mm);
        float den = a0 + a1;
        out[b * 2 + 0] = a0 / den;
        out[b * 2 + 1] = a1 / den;
    }
}

// ---------------------------------------------------------------------------
extern "C" void kernel_launch(void* const* d_in, const int* in_sizes, int n_in,
                              void* d_out, int out_size, void* d_ws,
                              size_t ws_size, hipStream_t stream) {
    const int*   x           = (const int*)d_in[0];
    const float* embed       = (const float*)d_in[1];
    const float* lstm_kernel = (const float*)d_in[2];
    const float* lstm_bias   = (const float*)d_in[3];
    const float* w_omega     = (const float*)d_in[4];
    const float* b_omega     = (const float*)d_in[5];
    const float* u_omega     = (const float*)d_in[6];
    const float* w           = (const float*)d_in[7];
    const float* bfin        = (const float*)d_in[8];
    float*       out         = (float*)d_out;

    char* ws = (char*)d_ws;
    f16*   WxT    = (f16*)(ws + 0);              //  524288 B
    f16*   WhT    = (f16*)(ws + 524288);         //  524288 B
    f16*   WomT   = (f16*)(ws + 1048576);        //   65536 B
    int*   seqlen = (int*)(ws + 1114112);        //    1024 B
    f16*   Hstate = (f16*)(ws + 1115136);        //  131072 B
    float* Cstate = (float*)(ws + 1246208);      //  262144 B
    f16*   Hex    = (f16*)(ws + 1508352);        //  262144 B (32 wg x 2 x 4KB)
    int*   flags  = (int*)(ws + 1770496);        //    4096 B (32 x 128 B)
    f16*   outs   = (f16*)(ws + 1774592);        // 67108864 B
    f16*   Zx     = (f16*)(ws + 1774592 + 67108864);

    const size_t fixed = 1774592ull + 67108864ull;
    int nch = 1;
    while (nch < 16 && fixed + 268435456ull / (size_t)nch > ws_size) nch <<= 1;
    int Tc = T_ / nch;

    k0_convert<<<1152, 256, 0, stream>>>(lstm_kernel, w_omega, WxT, WhT, WomT);
    k1_seqlen<<<256, 256, 0, stream>>>(x, seqlen, flags);
    for (int chk = 0; chk < nch; chk++) {
        int t0 = chk * Tc;
        k2_zx<<<(B_ * Tc) / 64, 256, 0, stream>>>(x, embed, WxT, lstm_bias, Zx,
                                                  t0, Tc);
        k3_lstm<<<32, 512, 0, stream>>>(Zx, WhT, seqlen, outs, Hstate, Cstate,
                                        Hex, flags, t0, Tc, chk == 0 ? 1 : 0,
                                        chk == nch - 1 ? 1 : 0);
    }
    k4_attn<<<256, 256, 0, stream>>>(outs, WomT, b_omega, u_omega, w, bfin, out);
}

// Round 6
// 1833.190 us; speedup vs baseline: 2.4117x; 1.2382x over previous
//
#include <hip/hip_runtime.h>
#include <hip/hip_bf16.h>
#include <cstdint>
#include <cstddef>

typedef _Float16 f16;
typedef _Float16 f16x8 __attribute__((ext_vector_type(8)));
typedef float f32x4 __attribute__((ext_vector_type(4)));
typedef unsigned long long u64;
typedef unsigned int u32;

#define B_   256
#define T_   512
#define V_   50000
#define D_   256
#define H_   256
#define A_   128
#define N4H  1024

__device__ __forceinline__ float sigmoid_f(float x) {
    return __builtin_amdgcn_rcpf(1.f + __expf(-x));
}
__device__ __forceinline__ float tanh_f(float x) {
    float e = __expf(-2.f * fabsf(x));
    float t = 1.f - 2.f * e * __builtin_amdgcn_rcpf(1.f + e);
    return copysignf(t, x);
}

// ---------------------------------------------------------------------------
// K0: weight transpose + fp32->fp16 cast.
// ---------------------------------------------------------------------------
__global__ __launch_bounds__(256) void k0_convert(
    const float* __restrict__ lstm_kernel, const float* __restrict__ w_omega,
    f16* __restrict__ WxT, f16* __restrict__ WhT, f16* __restrict__ WomT) {
    int blk = blockIdx.x;
    int tau = threadIdx.x;  // 0..255 (= k / h index)
    if (blk < N4H) {
        int n = blk;
        WxT[n * 256 + tau] = (f16)lstm_kernel[(size_t)tau * N4H + n];
        WhT[n * 256 + tau] = (f16)lstm_kernel[(size_t)(256 + tau) * N4H + n];
    } else {
        int a = blk - N4H;  // 0..127
        WomT[a * 256 + tau] = (f16)w_omega[(size_t)tau * A_ + a];
    }
}

// ---------------------------------------------------------------------------
// K1: seq_len[b] = sum_t (x[b,t] != 0)
// ---------------------------------------------------------------------------
__global__ __launch_bounds__(256) void k1_seqlen(
    const int* __restrict__ x, int* __restrict__ seqlen) {
    __shared__ int red[256];
    int b = blockIdx.x, tau = threadIdx.x;
    int cnt = (x[b * T_ + tau] != 0) + (x[b * T_ + tau + 256] != 0);
    red[tau] = cnt;
    __syncthreads();
    for (int s = 128; s > 0; s >>= 1) {
        if (tau < s) red[tau] += red[tau + s];
        __syncthreads();
    }
    if (tau == 0) seqlen[b] = red[0];
}

// ---------------------------------------------------------------------------
// K2: Zx[i][n'] = embed[x[i]] @ Wx + bias, fp16 out.  i = b*Tc + (t - t0).
// Columns written in pair-split layout: n' = half*512 + g*128 + u'
// (n = g*256 + half*128 + u'), so each k3 half-WG reads a contiguous 512.
// ---------------------------------------------------------------------------
__global__ __launch_bounds__(256) void k2_zx(
    const int* __restrict__ x, const float* __restrict__ embed,
    const f16* __restrict__ WxT, const float* __restrict__ bias,
    f16* __restrict__ Zx, int t0, int Tc) {
    __shared__ __align__(16) f16 A_s[64][264];   // [m][k], pad 8
    __shared__ __align__(16) f16 B_s[128][72];   // [n][k-slice], pad 8
    __shared__ int tok_s[64];

    int tau  = threadIdx.x;
    int bm   = blockIdx.x;
    int i0   = bm * 64;
    int wave = tau >> 6, lane = tau & 63;
    int q = lane >> 4, c = lane & 15;

    if (tau < 64) {
        int i  = i0 + tau;
        int bb = i / Tc, tr = i - bb * Tc;
        tok_s[tau] = x[bb * T_ + t0 + tr];
    }
    __syncthreads();

    // gather A: 64 rows x 256 f32 -> fp16 LDS. 4 threads/row, 16 float4 each.
    {
        int r = tau >> 2, quarter = tau & 3;
        const float4* src =
            (const float4*)(embed + (size_t)tok_s[r] * D_ + quarter * 64);
        f16* dst = &A_s[r][quarter * 64];
#pragma unroll
        for (int j = 0; j < 16; j++) {
            float4 v = src[j];
            dst[j * 4 + 0] = (f16)v.x;
            dst[j * 4 + 1] = (f16)v.y;
            dst[j * 4 + 2] = (f16)v.z;
            dst[j * 4 + 3] = (f16)v.w;
        }
    }

    for (int np = 0; np < 8; np++) {
        f32x4 acc[8];
#pragma unroll
        for (int ni = 0; ni < 8; ni++) acc[ni] = (f32x4){0.f, 0.f, 0.f, 0.f};

        for (int kt = 0; kt < 4; kt++) {
            __syncthreads();  // previous B_s consumers done
            {
                int n = tau >> 1, half = tau & 1;
                const f16x8* src = (const f16x8*)(WxT +
                    (size_t)(np * 128 + n) * 256 + kt * 64 + half * 32);
                f16x8* dst = (f16x8*)&B_s[n][half * 32];
#pragma unroll
                for (int j = 0; j < 4; j++) dst[j] = src[j];
            }
            __syncthreads();
#pragma unroll
            for (int s = 0; s < 2; s++) {
                f16x8 afrag =
                    *(const f16x8*)&A_s[wave * 16 + c][kt * 64 + s * 32 + q * 8];
#pragma unroll
                for (int ni = 0; ni < 8; ni++) {
                    f16x8 bfrag = *(const f16x8*)&B_s[ni * 16 + c][s * 32 + q * 8];
                    acc[ni] = __builtin_amdgcn_mfma_f32_16x16x32_f16(
                        afrag, bfrag, acc[ni], 0, 0, 0);
                }
            }
        }
        // epilogue for this n-pass (permuted column write)
#pragma unroll
        for (int ni = 0; ni < 8; ni++) {
            int n   = np * 128 + ni * 16 + c;
            int g   = n >> 8, rem = n & 255;
            int np2 = (rem >> 7) * 512 + g * 128 + (rem & 127);
            float bv = bias[n];
#pragma unroll
            for (int r = 0; r < 4; r++) {
                int row = i0 + wave * 16 + q * 4 + r;
                Zx[(size_t)row * N4H + np2] = (f16)(acc[ni][r] + bv);
            }
        }
    }
}

// ---------------------------------------------------------------------------
// K3: persistent LSTM. Wh in AGPRs (v_accvgpr stash, proven R5). 32 WGs x
// 512 thr; pair = wgid>>1 owns batch rows [16*pair,+16); half = wgid&1 owns
// hidden units [128*half,+128) for all 4 gates. Cross-WG h exchange uses
// TAG-IN-DATA: each h published as u32 (tag<<16 | f16bits) via relaxed
// agent-scope stores; partner polls its own 4 distinct words until tags
// match. No flags, no fences, ONE barrier per step.
// ---------------------------------------------------------------------------
__global__ __launch_bounds__(512, 2) void k3_lstm(
    const f16* __restrict__ Zx, const f16* __restrict__ WhT,
    const int* __restrict__ seqlen, f16* __restrict__ outs,
    f16* __restrict__ Hstate, float* __restrict__ Cstate,
    u32* __restrict__ Hex, int t0, int Tc, int first, int last) {
    __shared__ __align__(16) f16 Zx_s[2][16][520];  // [parity][row][512 cols]
    __shared__ __align__(16) f16 h_s[2][16][264];   // [parity][row][k]

    int tau  = threadIdx.x;
    int w    = tau >> 6, lane = tau & 63;
    int q = lane >> 4, c = lane & 15;
    int wgid = blockIdx.x;
    int pair = wgid >> 1, half = wgid & 1;
    int b0 = pair * 16;
    int u0 = half * 128, pu0 = (half ^ 1) * 128;
    int u  = u0 + w * 16 + c;   // this lane's hidden unit
    int col = w * 16 + c;       // column inside our 128-chunk
    int zu = col;               // column inside our 512 Zx chunk (per gate)

    u32* hexw_my = Hex + (size_t)wgid * 2 * 2048;        // [parity][16][128]
    u32* hexw_pr = Hex + (size_t)(wgid ^ 1) * 2 * 2048;

    // ---- load Wh fragments once and stash into AGPRs ----
    float wha[4][8][4];  // SROA -> 128 individual "a"-class scalars
#pragma unroll
    for (int g = 0; g < 4; g++)
#pragma unroll
        for (int kc = 0; kc < 8; kc++) {
            f16x8 f = *(const f16x8*)(WhT +
                (size_t)(g * 256 + u0 + w * 16 + c) * 256 + kc * 32 + q * 8);
            f32x4 t = __builtin_bit_cast(f32x4, f);
#pragma unroll
            for (int d = 0; d < 4; d++)
                asm volatile("v_accvgpr_write_b32 %0, %1"
                             : "=a"(wha[g][kc][d]) : "v"(t[d]));
        }

    // ---- init h_s ----
    if (first) {
        for (int idx = tau; idx < 2 * 16 * 264; idx += 512)
            ((f16*)h_s)[idx] = (f16)0.f;
    } else {
        int parity = t0 & 1;
        for (int idx = tau; idx < 16 * 256; idx += 512) {
            int r = idx >> 8, k = idx & 255;
            h_s[parity][r][k] = Hstate[(b0 + r) * H_ + k];
        }
    }

    float cst[4];
    int   sl[4];
#pragma unroll
    for (int r = 0; r < 4; r++) {
        int row = q * 4 + r;
        cst[r] = first ? 0.f : Cstate[(b0 + row) * H_ + u];
        sl[r]  = seqlen[b0 + row];
    }

    // Zx staging geometry: thread stages 32 B of row (tau>>5), cols (tau&31)*16
    int r_st = tau >> 5;
    int cc   = (tau & 31) * 16;
    const f16* zxrow = Zx + ((size_t)(b0 + r_st) * Tc) * N4H + half * 512 + cc;

    // prologue: fill Zx_s for step 0
    {
        const f16x8* src = (const f16x8*)zxrow;
        f16x8* dst = (f16x8*)&Zx_s[t0 & 1][r_st][cc];
        dst[0] = src[0];
        dst[1] = src[1];
    }
    // partner-read geometry: thread handles 4 words: row tau>>5, cols (tau&31)*4
    int rr = tau >> 5;
    int uu = (tau & 31) * 4;

    __syncthreads();

    for (int tt = 0; tt < Tc; tt++) {
        int t  = t0 + tt;
        int pr = t & 1, pw = pr ^ 1;

        // prefetch Zx for step tt+1 (in flight across MFMA+gate phase)
        int tn = (tt + 1 < Tc) ? tt + 1 : tt;
        const f16x8* psrc = (const f16x8*)(zxrow + (size_t)tn * N4H);
        f16x8 z0 = psrc[0];
        f16x8 z1 = psrc[1];

        // recurrent GEMM: 4 gate tiles, K=256, B rebuilt from AGPRs per use
        f32x4 acc[4];
#pragma unroll
        for (int g = 0; g < 4; g++) acc[g] = (f32x4){0.f, 0.f, 0.f, 0.f};
#pragma unroll
        for (int kc = 0; kc < 8; kc++) {
            f16x8 afrag = *(const f16x8*)&h_s[pr][c][kc * 32 + q * 8];
#pragma unroll
            for (int g = 0; g < 4; g++) {
                f32x4 bv;
#pragma unroll
                for (int d = 0; d < 4; d++)
                    asm volatile("v_accvgpr_read_b32 %0, %1"
                                 : "=v"(bv[d]) : "a"(wha[g][kc][d]));
                f16x8 bfrag = __builtin_bit_cast(f16x8, bv);
                acc[g] = __builtin_amdgcn_mfma_f32_16x16x32_f16(
                    afrag, bfrag, acc[g], 0, 0, 0);
            }
        }

        u32 tag = (u32)((t + 1) & 0xffff);

        // gates + state update (C layout: col=c, row=q*4+r); publish own h
        // immediately as tagged words (relaxed agent stores, no barrier)
#pragma unroll
        for (int r = 0; r < 4; r++) {
            int row = q * 4 + r;
            float zi = acc[0][r] + (float)Zx_s[pr][row][0 * 128 + zu];
            float zj = acc[1][r] + (float)Zx_s[pr][row][1 * 128 + zu];
            float zf = acc[2][r] + (float)Zx_s[pr][row][2 * 128 + zu];
            float zo = acc[3][r] + (float)Zx_s[pr][row][3 * 128 + zu];
            float ig = sigmoid_f(zi);
            float jg = tanh_f(zj);
            float fg = sigmoid_f(zf + 1.f);
            float og = sigmoid_f(zo);
            float cn = cst[r] * fg + ig * jg;
            float hn = tanh_f(cn) * og;
            bool  m  = (t < sl[r]);
            cst[r]   = m ? cn : cst[r];
            float hold = (float)h_s[pr][row][u];
            f16 hkeep = (f16)(m ? hn : hold);
            h_s[pw][row][u] = hkeep;
            u32 word = (tag << 16) |
                       (u32)(unsigned short)__builtin_bit_cast(short, hkeep);
            __hip_atomic_store(&hexw_my[pw * 2048 + row * 128 + col], word,
                               __ATOMIC_RELAXED, __HIP_MEMORY_SCOPE_AGENT);
            outs[((size_t)(b0 + row) * T_ + t) * H_ + u] = (f16)(m ? hn : 0.f);
        }

        // issue first poll attempt early (overlaps with Zx consume)
        const u32* pp = &hexw_pr[pw * 2048 + rr * 128 + uu];
        u32 v0 = __hip_atomic_load(pp + 0, __ATOMIC_RELAXED,
                                   __HIP_MEMORY_SCOPE_AGENT);
        u32 v1 = __hip_atomic_load(pp + 1, __ATOMIC_RELAXED,
                                   __HIP_MEMORY_SCOPE_AGENT);
        u32 v2 = __hip_atomic_load(pp + 2, __ATOMIC_RELAXED,
                                   __HIP_MEMORY_SCOPE_AGENT);
        u32 v3 = __hip_atomic_load(pp + 3, __ATOMIC_RELAXED,
                                   __HIP_MEMORY_SCOPE_AGENT);

        // consume Zx prefetch into other parity
        {
            f16x8* dst = (f16x8*)&Zx_s[pw][r_st][cc];
            dst[0] = z0;
            dst[1] = z1;
        }

        // poll partner's 4 words until all carry this step's tag
        while ((v0 >> 16) != tag || (v1 >> 16) != tag ||
               (v2 >> 16) != tag || (v3 >> 16) != tag) {
            v0 = __hip_atomic_load(pp + 0, __ATOMIC_RELAXED,
                                   __HIP_MEMORY_SCOPE_AGENT);
            v1 = __hip_atomic_load(pp + 1, __ATOMIC_RELAXED,
                                   __HIP_MEMORY_SCOPE_AGENT);
            v2 = __hip_atomic_load(pp + 2, __ATOMIC_RELAXED,
                                   __HIP_MEMORY_SCOPE_AGENT);
            v3 = __hip_atomic_load(pp + 3, __ATOMIC_RELAXED,
                                   __HIP_MEMORY_SCOPE_AGENT);
        }
        {
            u64 hw = (u64)(v0 & 0xffff) | ((u64)(v1 & 0xffff) << 16) |
                     ((u64)(v2 & 0xffff) << 32) | ((u64)(v3 & 0xffff) << 48);
            *(u64*)&h_s[pw][rr][pu0 + uu] = hw;
        }

        __syncthreads();  // h_s[pw] + Zx_s[pw] fully assembled for next step
    }

    if (!last) {
        int parity = (t0 + Tc) & 1;
        for (int idx = tau; idx < 16 * 128; idx += 512) {
            int r = idx >> 7, k = u0 + (idx & 127);
            Hstate[(b0 + r) * H_ + k] = h_s[parity][r][k];
        }
#pragma unroll
        for (int r = 0; r < 4; r++)
            Cstate[(b0 + q * 4 + r) * H_ + u] = cst[r];
    }
}

// ---------------------------------------------------------------------------
// K4: attention + head. One WG (256 thr) per batch row.
// ---------------------------------------------------------------------------
__global__ __launch_bounds__(256) void k4_attn(
    const f16* __restrict__ outs, const f16* __restrict__ WomT,
    const float* __restrict__ b_omega, const float* __restrict__ u_omega,
    const float* __restrict__ w, const float* __restrict__ bfin,
    float* __restrict__ out) {
    __shared__ __align__(16) f16 A_s[64][264];
    __shared__ __align__(16) f16 val_s[64][132];
    __shared__ float u_s[128];
    __shared__ float vu_s[512];
    __shared__ float red0[256], red1[256];

    int b = blockIdx.x, tau = threadIdx.x;
    int wave = tau >> 6, lane = tau & 63;
    int q = lane >> 4, c = lane & 15;

    if (tau < 128) u_s[tau] = u_omega[tau];
    float bom[8];
#pragma unroll
    for (int ni = 0; ni < 8; ni++) bom[ni] = b_omega[ni * 16 + c];

    for (int ch = 0; ch < 8; ch++) {
        int t0c = ch * 64;
        __syncthreads();  // protects A_s/val_s reuse (+ covers u_s init)
        {   // stage 64 rows of outs
            int r = tau >> 2, seg = tau & 3;
            const f16x8* src =
                (const f16x8*)(outs + ((size_t)b * T_ + t0c + r) * H_ + seg * 64);
            f16x8* dst = (f16x8*)&A_s[r][seg * 64];
#pragma unroll
            for (int j = 0; j < 8; j++) dst[j] = src[j];
        }
        __syncthreads();

        f32x4 acc[8];
#pragma unroll
        for (int ni = 0; ni < 8; ni++) acc[ni] = (f32x4){0.f, 0.f, 0.f, 0.f};
#pragma unroll
        for (int kc = 0; kc < 8; kc++) {
            f16x8 afrag = *(const f16x8*)&A_s[wave * 16 + c][kc * 32 + q * 8];
#pragma unroll
            for (int ni = 0; ni < 8; ni++) {
                f16x8 bfrag = *(const f16x8*)(WomT +
                    (size_t)(ni * 16 + c) * 256 + kc * 32 + q * 8);
                acc[ni] = __builtin_amdgcn_mfma_f32_16x16x32_f16(
                    afrag, bfrag, acc[ni], 0, 0, 0);
            }
        }
#pragma unroll
        for (int ni = 0; ni < 8; ni++) {
#pragma unroll
            for (int r = 0; r < 4; r++) {
                val_s[wave * 16 + q * 4 + r][ni * 16 + c] =
                    (f16)tanh_f(acc[ni][r] + bom[ni]);
            }
        }
        __syncthreads();
        if (tau < 64) {
            float s = 0.f;
#pragma unroll 8
            for (int a = 0; a < 128; a++) s += (float)val_s[tau][a] * u_s[a];
            vu_s[t0c + tau] = s;
        }
    }
    __syncthreads();

    // softmax over T=512
    red0[tau] = fmaxf(vu_s[tau], vu_s[tau + 256]);
    __syncthreads();
    for (int s = 128; s > 0; s >>= 1) {
        if (tau < s) red0[tau] = fmaxf(red0[tau], red0[tau + s]);
        __syncthreads();
    }
    float mx = red0[0];
    __syncthreads();
    float e0 = __expf(vu_s[tau] - mx), e1 = __expf(vu_s[tau + 256] - mx);
    red0[tau] = e0 + e1;
    __syncthreads();
    for (int s = 128; s > 0; s >>= 1) {
        if (tau < s) red0[tau] += red0[tau + s];
        __syncthreads();
    }
    float inv = 1.f / red0[0];
    __syncthreads();
    vu_s[tau]       = e0 * inv;
    vu_s[tau + 256] = e1 * inv;
    __syncthreads();

    // last[h] = sum_t alpha[t] * outs[b][t][h]   (tau = h)
    float lastv = 0.f;
#pragma unroll 4
    for (int t = 0; t < T_; t++)
        lastv += vu_s[t] * (float)outs[((size_t)b * T_ + t) * H_ + tau];

    // logits + 2-class softmax
    red0[tau] = lastv * w[tau * 2 + 0];
    red1[tau] = lastv * w[tau * 2 + 1];
    __syncthreads();
    for (int s = 128; s > 0; s >>= 1) {
        if (tau < s) {
            red0[tau] += red0[tau + s];
            red1[tau] += red1[tau + s];
        }
        __syncthreads();
    }
    if (tau == 0) {
        float l0 = red0[0] + bfin[0], l1 = red1[0] + bfin[1];
        float mm = fmaxf(l0, l1);
        float a0 = __expf(l0 - mm), a1 = __expf(l1 - mm);
        float den = a0 + a1;
        out[b * 2 + 0] = a0 / den;
        out[b * 2 + 1] = a1 / den;
    }
}

// ---------------------------------------------------------------------------
extern "C" void kernel_launch(void* const* d_in, const int* in_sizes, int n_in,
                              void* d_out, int out_size, void* d_ws,
                              size_t ws_size, hipStream_t stream) {
    const int*   x           = (const int*)d_in[0];
    const float* embed       = (const float*)d_in[1];
    const float* lstm_kernel = (const float*)d_in[2];
    const float* lstm_bias   = (const float*)d_in[3];
    const float* w_omega     = (const float*)d_in[4];
    const float* b_omega     = (const float*)d_in[5];
    const float* u_omega     = (const float*)d_in[6];
    const float* w           = (const float*)d_in[7];
    const float* bfin        = (const float*)d_in[8];
    float*       out         = (float*)d_out;

    char* ws = (char*)d_ws;
    f16*   WxT    = (f16*)(ws + 0);              //  524288 B
    f16*   WhT    = (f16*)(ws + 524288);         //  524288 B
    f16*   WomT   = (f16*)(ws + 1048576);        //   65536 B
    int*   seqlen = (int*)(ws + 1114112);        //    1024 B
    f16*   Hstate = (f16*)(ws + 1115136);        //  131072 B
    float* Cstate = (float*)(ws + 1246208);      //  262144 B
    u32*   Hex    = (u32*)(ws + 1508352);        //  524288 B (32 wg x 2 x 8KB)
    f16*   outs   = (f16*)(ws + 2032640);        // 67108864 B
    f16*   Zx     = (f16*)(ws + 2032640 + 67108864);

    const size_t fixed = 2032640ull + 67108864ull;
    int nch = 1;
    while (nch < 16 && fixed + 268435456ull / (size_t)nch > ws_size) nch <<= 1;
    int Tc = T_ / nch;

    k0_convert<<<1152, 256, 0, stream>>>(lstm_kernel, w_omega, WxT, WhT, WomT);
    k1_seqlen<<<256, 256, 0, stream>>>(x, seqlen);
    for (int chk = 0; chk < nch; chk++) {
        int t0 = chk * Tc;
        k2_zx<<<(B_ * Tc) / 64, 256, 0, stream>>>(x, embed, WxT, lstm_bias, Zx,
                                                  t0, Tc);
        k3_lstm<<<32, 512, 0, stream>>>(Zx, WhT, seqlen, outs, Hstate, Cstate,
                                        Hex, t0, Tc, chk == 0 ? 1 : 0,
                                        chk == nch - 1 ? 1 : 0);
    }
    k4_attn<<<256, 256, 0, stream>>>(outs, WomT, b_omega, u_omega, w, bfin, out);
}

// Round 7
// 1596.884 us; speedup vs baseline: 2.7686x; 1.1480x over previous
//
#include <hip/hip_runtime.h>
#include <hip/hip_bf16.h>
#include <cstdint>
#include <cstddef>

typedef _Float16 f16;
typedef _Float16 f16x8 __attribute__((ext_vector_type(8)));
typedef _Float16 f16x4 __attribute__((ext_vector_type(4)));
typedef float f32x4 __attribute__((ext_vector_type(4)));
typedef unsigned long long u64;
typedef unsigned int u32;

#define B_   256
#define T_   512
#define V_   50000
#define D_   256
#define H_   256
#define A_   128
#define N4H  1024

__device__ __forceinline__ float sigmoid_f(float x) {
    return __builtin_amdgcn_rcpf(1.f + __expf(-x));
}
__device__ __forceinline__ float tanh_f(float x) {
    float e = __expf(-2.f * fabsf(x));
    float t = 1.f - 2.f * e * __builtin_amdgcn_rcpf(1.f + e);
    return copysignf(t, x);
}

// asm MFMA with B operand taken straight from AGPRs (no accvgpr_read moves)
#define MFMA_A(accv, afragv, bfraga)                                         \
    asm volatile("v_mfma_f32_16x16x32_f16 %0, %1, %2, %0"                    \
                 : "+v"(accv) : "v"(afragv), "a"(bfraga))

// ---------------------------------------------------------------------------
// K0: weight transpose + fp32->fp16 cast.
// ---------------------------------------------------------------------------
__global__ __launch_bounds__(256) void k0_convert(
    const float* __restrict__ lstm_kernel, const float* __restrict__ w_omega,
    f16* __restrict__ WxT, f16* __restrict__ WhT, f16* __restrict__ WomT) {
    int blk = blockIdx.x;
    int tau = threadIdx.x;  // 0..255 (= k / h index)
    if (blk < N4H) {
        int n = blk;
        WxT[n * 256 + tau] = (f16)lstm_kernel[(size_t)tau * N4H + n];
        WhT[n * 256 + tau] = (f16)lstm_kernel[(size_t)(256 + tau) * N4H + n];
    } else {
        int a = blk - N4H;  // 0..127
        WomT[a * 256 + tau] = (f16)w_omega[(size_t)tau * A_ + a];
    }
}

// ---------------------------------------------------------------------------
// K1: seq_len[b] = sum_t (x[b,t] != 0)
// ---------------------------------------------------------------------------
__global__ __launch_bounds__(256) void k1_seqlen(
    const int* __restrict__ x, int* __restrict__ seqlen) {
    __shared__ int red[256];
    int b = blockIdx.x, tau = threadIdx.x;
    int cnt = (x[b * T_ + tau] != 0) + (x[b * T_ + tau + 256] != 0);
    red[tau] = cnt;
    __syncthreads();
    for (int s = 128; s > 0; s >>= 1) {
        if (tau < s) red[tau] += red[tau + s];
        __syncthreads();
    }
    if (tau == 0) seqlen[b] = red[0];
}

// ---------------------------------------------------------------------------
// K2: Zx = embed[x] @ Wx + bias, fp16.  Column layout is half-split AND
// gate-interleaved: n = g*256 + half*128 + colu  ->  n'' = half*512 + colu*4 + g
// so k3 reads {i,j,f,o} for one unit as ONE ds_read_b64.
// ---------------------------------------------------------------------------
__global__ __launch_bounds__(256) void k2_zx(
    const int* __restrict__ x, const float* __restrict__ embed,
    const f16* __restrict__ WxT, const float* __restrict__ bias,
    f16* __restrict__ Zx, int t0, int Tc) {
    __shared__ __align__(16) f16 A_s[64][264];   // [m][k], pad 8
    __shared__ __align__(16) f16 B_s[128][72];   // [n][k-slice], pad 8
    __shared__ int tok_s[64];

    int tau  = threadIdx.x;
    int bm   = blockIdx.x;
    int i0   = bm * 64;
    int wave = tau >> 6, lane = tau & 63;
    int q = lane >> 4, c = lane & 15;

    if (tau < 64) {
        int i  = i0 + tau;
        int bb = i / Tc, tr = i - bb * Tc;
        tok_s[tau] = x[bb * T_ + t0 + tr];
    }
    __syncthreads();

    // gather A: 64 rows x 256 f32 -> fp16 LDS. 4 threads/row, 16 float4 each.
    {
        int r = tau >> 2, quarter = tau & 3;
        const float4* src =
            (const float4*)(embed + (size_t)tok_s[r] * D_ + quarter * 64);
        f16* dst = &A_s[r][quarter * 64];
#pragma unroll
        for (int j = 0; j < 16; j++) {
            float4 v = src[j];
            dst[j * 4 + 0] = (f16)v.x;
            dst[j * 4 + 1] = (f16)v.y;
            dst[j * 4 + 2] = (f16)v.z;
            dst[j * 4 + 3] = (f16)v.w;
        }
    }

    for (int np = 0; np < 8; np++) {
        f32x4 acc[8];
#pragma unroll
        for (int ni = 0; ni < 8; ni++) acc[ni] = (f32x4){0.f, 0.f, 0.f, 0.f};

        for (int kt = 0; kt < 4; kt++) {
            __syncthreads();  // previous B_s consumers done
            {
                int n = tau >> 1, half = tau & 1;
                const f16x8* src = (const f16x8*)(WxT +
                    (size_t)(np * 128 + n) * 256 + kt * 64 + half * 32);
                f16x8* dst = (f16x8*)&B_s[n][half * 32];
#pragma unroll
                for (int j = 0; j < 4; j++) dst[j] = src[j];
            }
            __syncthreads();
#pragma unroll
            for (int s = 0; s < 2; s++) {
                f16x8 afrag =
                    *(const f16x8*)&A_s[wave * 16 + c][kt * 64 + s * 32 + q * 8];
#pragma unroll
                for (int ni = 0; ni < 8; ni++) {
                    f16x8 bfrag = *(const f16x8*)&B_s[ni * 16 + c][s * 32 + q * 8];
                    acc[ni] = __builtin_amdgcn_mfma_f32_16x16x32_f16(
                        afrag, bfrag, acc[ni], 0, 0, 0);
                }
            }
        }
        // epilogue (half-split + gate-interleaved column write)
#pragma unroll
        for (int ni = 0; ni < 8; ni++) {
            int n    = np * 128 + ni * 16 + c;
            int g    = n >> 8, rem = n & 255;
            int half = rem >> 7, colu = rem & 127;
            int np2  = half * 512 + colu * 4 + g;
            float bv = bias[n];
#pragma unroll
            for (int r = 0; r < 4; r++) {
                int row = i0 + wave * 16 + q * 4 + r;
                Zx[(size_t)row * N4H + np2] = (f16)(acc[ni][r] + bv);
            }
        }
    }
}

// ---------------------------------------------------------------------------
// K3: persistent LSTM, split-K pipelined pair exchange.
// 32 WGs x 512 thr; pair = wgid>>1 owns rows [16*pair,+16); half = wgid&1
// owns units [128*half,+128) x 4 gates. Wh slice pinned in AGPRs (opaque
// "=a" asm) and consumed DIRECTLY as MFMA B operand (no accvgpr_read).
// Per step: [poll+merge partner h_t] -> barrier -> partner-half K MFMA ->
// gates -> publish tagged h (L3) -> issue polls -> Zx consume -> outs ->
// barrier -> own-half K MFMA for t+1 (covers the exchange RTT).
// Wh AGPR slots stored own-half-first so register indices are compile-time.
// ---------------------------------------------------------------------------
__global__ __launch_bounds__(512, 2) void k3_lstm(
    const f16* __restrict__ Zx, const f16* __restrict__ WhT,
    const int* __restrict__ seqlen, f16* __restrict__ outs,
    f16* __restrict__ Hstate, float* __restrict__ Cstate,
    u32* __restrict__ Hex, int t0, int Tc, int first, int last) {
    __shared__ __align__(16) f16 Zx_s[2][16][520];  // [parity][row][512 cols]
    __shared__ __align__(16) f16 h_s[2][16][264];   // [parity][row][k]

    int tau  = threadIdx.x;
    int w    = tau >> 6, lane = tau & 63;
    int q = lane >> 4, c = lane & 15;
    int wgid = blockIdx.x;
    int pair = wgid >> 1, half = wgid & 1;
    int b0 = pair * 16;
    int u0 = half * 128, pu0 = (half ^ 1) * 128;
    int u  = u0 + w * 16 + c;   // this lane's hidden unit
    int col = w * 16 + c;       // unit index inside our 128-chunk

    u32* hexw_my = Hex + (size_t)wgid * 2 * 2048;        // [parity][16][128]
    u32* hexw_pr = Hex + (size_t)(wgid ^ 1) * 2 * 2048;

    // ---- Wh fragments pinned in AGPRs; slot s<4 = own-half K, s>=4 partner ----
    f32x4 wha[4][8];
#pragma unroll
    for (int g = 0; g < 4; g++)
#pragma unroll
        for (int s = 0; s < 8; s++) {
            int kc = (s < 4) ? (half * 4 + s) : ((half ^ 1) * 4 + (s - 4));
            f16x8 f = *(const f16x8*)(WhT +
                (size_t)(g * 256 + u0 + w * 16 + c) * 256 + kc * 32 + q * 8);
            f32x4 t = __builtin_bit_cast(f32x4, f);
            asm volatile("" : "=a"(wha[g][s]) : "0"(t));
        }

    // k-element offsets within an h_s row for the two K-halves
    int kOwn = half * 128 + q * 8;          // + kk*32
    int kPar = (half ^ 1) * 128 + q * 8;

    // ---- init h_s / cst / hprev ----
    int p0 = t0 & 1;
    if (first) {
        for (int idx = tau; idx < 2 * 16 * 264; idx += 512)
            ((f16*)h_s)[idx] = (f16)0.f;
    } else {
        for (int idx = tau; idx < 16 * 256; idx += 512) {
            int r = idx >> 8, k = idx & 255;
            h_s[p0][r][k] = Hstate[(b0 + r) * H_ + k];
        }
    }

    float cst[4];
    f16   hprev[4];
    int   sl[4];
#pragma unroll
    for (int r = 0; r < 4; r++) {
        int row = q * 4 + r;
        cst[r]   = first ? 0.f : Cstate[(b0 + row) * H_ + u];
        hprev[r] = first ? (f16)0.f : Hstate[(b0 + row) * H_ + u];
        sl[r]    = seqlen[b0 + row];
    }

    // Zx staging geometry: thread stages 32 B of row (tau>>5), cols (tau&31)*16
    int r_st = tau >> 5;
    int cc   = (tau & 31) * 16;
    const f16* zxrow = Zx + ((size_t)(b0 + r_st) * Tc) * N4H + half * 512 + cc;

    // prologue: fill Zx_s for step 0
    {
        const f16x8* src = (const f16x8*)zxrow;
        f16x8* dst = (f16x8*)&Zx_s[p0][r_st][cc];
        dst[0] = src[0];
        dst[1] = src[1];
    }
    // partner-merge geometry: thread handles 4 words: row tau>>5, cols (tau&31)*4
    int rr = tau >> 5;
    int uu = (tau & 31) * 4;

    __syncthreads();

    // prologue: own-half partial MFMA from h_s[p0]
    f32x4 accO[4];
#pragma unroll
    for (int g = 0; g < 4; g++) accO[g] = (f32x4){0.f, 0.f, 0.f, 0.f};
#pragma unroll
    for (int kk = 0; kk < 4; kk++) {
        f16x8 afrag = *(const f16x8*)&h_s[p0][c][kOwn + kk * 32];
#pragma unroll
        for (int g = 0; g < 4; g++) MFMA_A(accO[g], afrag, wha[g][kk]);
    }

    u64 vp0 = 0, vp1 = 0;  // in-flight partner poll payload

    for (int tt = 0; tt < Tc; tt++) {
        int t   = t0 + tt;
        int cur = t & 1, nxt = cur ^ 1;

        // Zx prefetch for t+1 (max latency cover: consumed end of iteration)
        int tn = (tt + 1 < Tc) ? tt + 1 : tt;
        const f16x8* psrc = (const f16x8*)(zxrow + (size_t)tn * N4H);
        f16x8 z0 = psrc[0];
        f16x8 z1 = psrc[1];

        // poll + merge partner half of h_t (skip at chunk start: h_s complete)
        if (tt > 0) {
            u32 tagp = (u32)(t & 0xffff);
            const u64* pp = (const u64*)&hexw_pr[cur * 2048 + rr * 128 + uu];
            while (((u32)(vp0 >> 16) & 0xffffu) != tagp ||
                   ((u32)(vp0 >> 48)) != tagp ||
                   ((u32)(vp1 >> 16) & 0xffffu) != tagp ||
                   ((u32)(vp1 >> 48)) != tagp) {
                vp0 = __hip_atomic_load(pp + 0, __ATOMIC_RELAXED,
                                        __HIP_MEMORY_SCOPE_AGENT);
                vp1 = __hip_atomic_load(pp + 1, __ATOMIC_RELAXED,
                                        __HIP_MEMORY_SCOPE_AGENT);
            }
            u64 hw = (u64)(vp0 & 0xffff) | (((vp0 >> 32) & 0xffff) << 16) |
                     ((vp1 & 0xffff) << 32) | (((vp1 >> 32) & 0xffff) << 48);
            *(u64*)&h_s[cur][rr][pu0 + uu] = hw;
        }
        __syncthreads();  // partner half visible; h_s[cur] complete

        // partner-half K MFMA (slots 4-7) -> full pre-activations in accO
#pragma unroll
        for (int kk = 0; kk < 4; kk++) {
            f16x8 afrag = *(const f16x8*)&h_s[cur][c][kPar + kk * 32];
#pragma unroll
            for (int g = 0; g < 4; g++) MFMA_A(accO[g], afrag, wha[g][4 + kk]);
        }

        // gates (C layout: col=c, row=q*4+r); publish own h with tag t+1
        u32 tag = (u32)((t + 1) & 0xffff);
        f16 ovals[4];
#pragma unroll
        for (int r = 0; r < 4; r++) {
            int row = q * 4 + r;
            f16x4 zv = *(const f16x4*)&Zx_s[cur][row][col * 4];
            float zi = accO[0][r] + (float)zv[0];
            float zj = accO[1][r] + (float)zv[1];
            float zf = accO[2][r] + (float)zv[2];
            float zo = accO[3][r] + (float)zv[3];
            float ig = sigmoid_f(zi);
            float jg = tanh_f(zj);
            float fg = sigmoid_f(zf + 1.f);
            float og = sigmoid_f(zo);
            float cn = cst[r] * fg + ig * jg;
            float hn = tanh_f(cn) * og;
            bool  m  = (t < sl[r]);
            cst[r]   = m ? cn : cst[r];
            f16 hkeep = m ? (f16)hn : hprev[r];
            hprev[r]  = hkeep;
            h_s[nxt][row][u] = hkeep;
            u32 word = (tag << 16) |
                       (u32)(unsigned short)__builtin_bit_cast(short, hkeep);
            __hip_atomic_store(&hexw_my[nxt * 2048 + row * 128 + col], word,
                               __ATOMIC_RELAXED, __HIP_MEMORY_SCOPE_AGENT);
            ovals[r] = m ? (f16)hn : (f16)0.f;
        }

        // issue partner polls for h_{t+1} BEFORE outs stores (vmcnt in-order:
        // waiting on these loads later won't drain the HBM stores)
        {
            const u64* pp2 = (const u64*)&hexw_pr[nxt * 2048 + rr * 128 + uu];
            vp0 = __hip_atomic_load(pp2 + 0, __ATOMIC_RELAXED,
                                    __HIP_MEMORY_SCOPE_AGENT);
            vp1 = __hip_atomic_load(pp2 + 1, __ATOMIC_RELAXED,
                                    __HIP_MEMORY_SCOPE_AGENT);
        }

        // consume Zx prefetch into other parity
        {
            f16x8* dst = (f16x8*)&Zx_s[nxt][r_st][cc];
            dst[0] = z0;
            dst[1] = z1;
        }

        // outs stores (after poll issue)
#pragma unroll
        for (int r = 0; r < 4; r++)
            outs[((size_t)(b0 + q * 4 + r) * T_ + t) * H_ + u] = ovals[r];

        __syncthreads();  // own half of h_s[nxt] + Zx_s[nxt] ready

        // own-half K MFMA for step t+1 (slots 0-3) — covers exchange RTT
#pragma unroll
        for (int g = 0; g < 4; g++) accO[g] = (f32x4){0.f, 0.f, 0.f, 0.f};
#pragma unroll
        for (int kk = 0; kk < 4; kk++) {
            f16x8 afrag = *(const f16x8*)&h_s[nxt][c][kOwn + kk * 32];
#pragma unroll
            for (int g = 0; g < 4; g++) MFMA_A(accO[g], afrag, wha[g][kk]);
        }
    }

    if (!last) {
        int parity = (t0 + Tc) & 1;
        for (int idx = tau; idx < 16 * 128; idx += 512) {
            int r = idx >> 7, k = u0 + (idx & 127);
            Hstate[(b0 + r) * H_ + k] = h_s[parity][r][k];
        }
#pragma unroll
        for (int r = 0; r < 4; r++)
            Cstate[(b0 + q * 4 + r) * H_ + u] = cst[r];
    }
}

// ---------------------------------------------------------------------------
// K4: attention + head. One WG (256 thr) per batch row.
// ---------------------------------------------------------------------------
__global__ __launch_bounds__(256) void k4_attn(
    const f16* __restrict__ outs, const f16* __restrict__ WomT,
    const float* __restrict__ b_omega, const float* __restrict__ u_omega,
    const float* __restrict__ w, const float* __restrict__ bfin,
    float* __restrict__ out) {
    __shared__ __align__(16) f16 A_s[64][264];
    __shared__ __align__(16) f16 val_s[64][132];
    __shared__ float u_s[128];
    __shared__ float vu_s[512];
    __shared__ float red0[256], red1[256];

    int b = blockIdx.x, tau = threadIdx.x;
    int wave = tau >> 6, lane = tau & 63;
    int q = lane >> 4, c = lane & 15;

    if (tau < 128) u_s[tau] = u_omega[tau];
    float bom[8];
#pragma unroll
    for (int ni = 0; ni < 8; ni++) bom[ni] = b_omega[ni * 16 + c];

    for (int ch = 0; ch < 8; ch++) {
        int t0c = ch * 64;
        __syncthreads();  // protects A_s/val_s reuse (+ covers u_s init)
        {   // stage 64 rows of outs
            int r = tau >> 2, seg = tau & 3;
            const f16x8* src =
                (const f16x8*)(outs + ((size_t)b * T_ + t0c + r) * H_ + seg * 64);
            f16x8* dst = (f16x8*)&A_s[r][seg * 64];
#pragma unroll
            for (int j = 0; j < 8; j++) dst[j] = src[j];
        }
        __syncthreads();

        f32x4 acc[8];
#pragma unroll
        for (int ni = 0; ni < 8; ni++) acc[ni] = (f32x4){0.f, 0.f, 0.f, 0.f};
#pragma unroll
        for (int kc = 0; kc < 8; kc++) {
            f16x8 afrag = *(const f16x8*)&A_s[wave * 16 + c][kc * 32 + q * 8];
#pragma unroll
            for (int ni = 0; ni < 8; ni++) {
                f16x8 bfrag = *(const f16x8*)(WomT +
                    (size_t)(ni * 16 + c) * 256 + kc * 32 + q * 8);
                acc[ni] = __builtin_amdgcn_mfma_f32_16x16x32_f16(
                    afrag, bfrag, acc[ni], 0, 0, 0);
            }
        }
#pragma unroll
        for (int ni = 0; ni < 8; ni++) {
#pragma unroll
            for (int r = 0; r < 4; r++) {
                val_s[wave * 16 + q * 4 + r][ni * 16 + c] =
                    (f16)tanh_f(acc[ni][r] + bom[ni]);
            }
        }
        __syncthreads();
        if (tau < 64) {
            float s = 0.f;
#pragma unroll 8
            for (int a = 0; a < 128; a++) s += (float)val_s[tau][a] * u_s[a];
            vu_s[t0c + tau] = s;
        }
    }
    __syncthreads();

    // softmax over T=512
    red0[tau] = fmaxf(vu_s[tau], vu_s[tau + 256]);
    __syncthreads();
    for (int s = 128; s > 0; s >>= 1) {
        if (tau < s) red0[tau] = fmaxf(red0[tau], red0[tau + s]);
        __syncthreads();
    }
    float mx = red0[0];
    __syncthreads();
    float e0 = __expf(vu_s[tau] - mx), e1 = __expf(vu_s[tau + 256] - mx);
    red0[tau] = e0 + e1;
    __syncthreads();
    for (int s = 128; s > 0; s >>= 1) {
        if (tau < s) red0[tau] += red0[tau + s];
        __syncthreads();
    }
    float inv = 1.f / red0[0];
    __syncthreads();
    vu_s[tau]       = e0 * inv;
    vu_s[tau + 256] = e1 * inv;
    __syncthreads();

    // last[h] = sum_t alpha[t] * outs[b][t][h]   (tau = h)
    float lastv = 0.f;
#pragma unroll 4
    for (int t = 0; t < T_; t++)
        lastv += vu_s[t] * (float)outs[((size_t)b * T_ + t) * H_ + tau];

    // logits + 2-class softmax
    red0[tau] = lastv * w[tau * 2 + 0];
    red1[tau] = lastv * w[tau * 2 + 1];
    __syncthreads();
    for (int s = 128; s > 0; s >>= 1) {
        if (tau < s) {
            red0[tau] += red0[tau + s];
            red1[tau] += red1[tau + s];
        }
        __syncthreads();
    }
    if (tau == 0) {
        float l0 = red0[0] + bfin[0], l1 = red1[0] + bfin[1];
        float mm = fmaxf(l0, l1);
        float a0 = __expf(l0 - mm), a1 = __expf(l1 - mm);
        float den = a0 + a1;
        out[b * 2 + 0] = a0 / den;
        out[b * 2 + 1] = a1 / den;
    }
}

// ---------------------------------------------------------------------------
extern "C" void kernel_launch(void* const* d_in, const int* in_sizes, int n_in,
                              void* d_out, int out_size, void* d_ws,
                              size_t ws_size, hipStream_t stream) {
    const int*   x           = (const int*)d_in[0];
    const float* embed       = (const float*)d_in[1];
    const float* lstm_kernel = (const float*)d_in[2];
    const float* lstm_bias   = (const float*)d_in[3];
    const float* w_omega     = (const float*)d_in[4];
    const float* b_omega     = (const float*)d_in[5];
    const float* u_omega     = (const float*)d_in[6];
    const float* w           = (const float*)d_in[7];
    const float* bfin        = (const float*)d_in[8];
    float*       out         = (float*)d_out;

    char* ws = (char*)d_ws;
    f16*   WxT    = (f16*)(ws + 0);              //  524288 B
    f16*   WhT    = (f16*)(ws + 524288);         //  524288 B
    f16*   WomT   = (f16*)(ws + 1048576);        //   65536 B
    int*   seqlen = (int*)(ws + 1114112);        //    1024 B
    f16*   Hstate = (f16*)(ws + 1115136);        //  131072 B
    float* Cstate = (float*)(ws + 1246208);      //  262144 B
    u32*   Hex    = (u32*)(ws + 1508352);        //  524288 B (32 wg x 2 x 8KB)
    f16*   outs   = (f16*)(ws + 2032640);        // 67108864 B
    f16*   Zx     = (f16*)(ws + 2032640 + 67108864);

    const size_t fixed = 2032640ull + 67108864ull;
    int nch = 1;
    while (nch < 16 && fixed + 268435456ull / (size_t)nch > ws_size) nch <<= 1;
    int Tc = T_ / nch;

    k0_convert<<<1152, 256, 0, stream>>>(lstm_kernel, w_omega, WxT, WhT, WomT);
    k1_seqlen<<<256, 256, 0, stream>>>(x, seqlen);
    for (int chk = 0; chk < nch; chk++) {
        int t0 = chk * Tc;
        k2_zx<<<(B_ * Tc) / 64, 256, 0, stream>>>(x, embed, WxT, lstm_bias, Zx,
                                                  t0, Tc);
        k3_lstm<<<32, 512, 0, stream>>>(Zx, WhT, seqlen, outs, Hstate, Cstate,
                                        Hex, t0, Tc, chk == 0 ? 1 : 0,
                                        chk == nch - 1 ? 1 : 0);
    }
    k4_attn<<<256, 256, 0, stream>>>(outs, WomT, b_omega, u_omega, w, bfin, out);
}